// Round 8
// baseline (1933.401 us; speedup 1.0000x reference)
//
#include <hip/hip_runtime.h>
#include <math.h>

#define NN 50000
#define EE 600000
#define CD 128
#define FD 512
#define NCF 6400000.0   // NN*CD as double

__device__ __forceinline__ float4 ld4(const float* p){ return *(const float4*)p; }

// ---------------- GEMM: q,k,v,skip = x @ {Wq,Wk,Wv,Wskip} + bias ----------------
__global__ __launch_bounds__(256) void qkvs_gemm(
    const float* __restrict__ x,
    const float* __restrict__ Wq, const float* __restrict__ bq,
    const float* __restrict__ Wk, const float* __restrict__ bk,
    const float* __restrict__ Wv, const float* __restrict__ bv,
    const float* __restrict__ Wsk, const float* __restrict__ bsk,
    float* __restrict__ oq, float* __restrict__ okk,
    float* __restrict__ ov, float* __restrict__ osk)
{
    __shared__ float ast[32*132];
    __shared__ float bst[32*132];
    const int tid = threadIdx.x;
    const int r0 = blockIdx.x * 128;
    const float* W; const float* bias; float* out;
    switch (blockIdx.y) {
        case 0:  W = Wq;  bias = bq;  out = oq;  break;
        case 1:  W = Wk;  bias = bk;  out = okk; break;
        case 2:  W = Wv;  bias = bv;  out = ov;  break;
        default: W = Wsk; bias = bsk; out = osk; break;
    }
    const int tc = tid & 15, tr = tid >> 4;
    float acc[8][8];
    #pragma unroll
    for (int i = 0; i < 8; ++i)
        #pragma unroll
        for (int j = 0; j < 8; ++j) acc[i][j] = 0.f;

    for (int kc = 0; kc < 4; ++kc) {
        #pragma unroll
        for (int it = 0; it < 4; ++it) {
            int chunk = it*256 + tid;
            int row = chunk >> 3, c4 = chunk & 7;
            float4 g = make_float4(0.f,0.f,0.f,0.f);
            if (r0 + row < NN) g = ld4(&x[(r0+row)*CD + kc*32 + c4*4]);
            ast[(c4*4+0)*132 + row] = g.x;
            ast[(c4*4+1)*132 + row] = g.y;
            ast[(c4*4+2)*132 + row] = g.z;
            ast[(c4*4+3)*132 + row] = g.w;
        }
        #pragma unroll
        for (int it = 0; it < 4; ++it) {
            int chunk = it*256 + tid;
            int kr = chunk >> 5, c4 = chunk & 31;
            *(float4*)&bst[kr*132 + c4*4] = ld4(&W[(kc*32+kr)*CD + c4*4]);
        }
        __syncthreads();
        #pragma unroll
        for (int k = 0; k < 32; ++k) {
            float4 a0 = *(float4*)&ast[k*132 + tr*8];
            float4 a1 = *(float4*)&ast[k*132 + tr*8 + 4];
            float4 b0 = *(float4*)&bst[k*132 + tc*8];
            float4 b1 = *(float4*)&bst[k*132 + tc*8 + 4];
            float ar[8] = {a0.x,a0.y,a0.z,a0.w,a1.x,a1.y,a1.z,a1.w};
            float br[8] = {b0.x,b0.y,b0.z,b0.w,b1.x,b1.y,b1.z,b1.w};
            #pragma unroll
            for (int i = 0; i < 8; ++i)
                #pragma unroll
                for (int j = 0; j < 8; ++j)
                    acc[i][j] += ar[i]*br[j];
        }
        __syncthreads();
    }
    float bcol[8];
    #pragma unroll
    for (int j = 0; j < 8; ++j) bcol[j] = bias[tc*8+j];
    #pragma unroll
    for (int i = 0; i < 8; ++i) {
        int row = r0 + tr*8 + i;
        if (row < NN) {
            float4 o0 = make_float4(acc[i][0]+bcol[0], acc[i][1]+bcol[1],
                                    acc[i][2]+bcol[2], acc[i][3]+bcol[3]);
            float4 o1 = make_float4(acc[i][4]+bcol[4], acc[i][5]+bcol[5],
                                    acc[i][6]+bcol[6], acc[i][7]+bcol[7]);
            *(float4*)&out[row*CD + tc*8]     = o0;
            *(float4*)&out[row*CD + tc*8 + 4] = o1;
        }
    }
}

// ---------------- CSR build ----------------
__global__ __launch_bounds__(256) void hist_kernel(const int* __restrict__ ei, int* __restrict__ cnt)
{
    int j = blockIdx.x*blockDim.x + threadIdx.x;
    if (j < EE) atomicAdd(&cnt[ei[EE + j]], 1);
}

__global__ __launch_bounds__(256) void scan_kernel(int* __restrict__ cnt, int* __restrict__ off)
{
    __shared__ int part[256];
    const int t = threadIdx.x;
    const int nper = (NN + 255) / 256;
    const int lo = t*nper, hi = min(lo + nper, NN);
    int ssum = 0;
    for (int i = lo; i < hi; ++i) ssum += cnt[i];
    part[t] = ssum;
    __syncthreads();
    if (t == 0) {
        int run = 0;
        for (int i = 0; i < 256; ++i) { int tmp = part[i]; part[i] = run; run += tmp; }
    }
    __syncthreads();
    int run = part[t];
    for (int i = lo; i < hi; ++i) {
        int c = cnt[i];
        off[i] = run;
        cnt[i] = run;
        run += c;
    }
    if (hi == NN) off[NN] = run;
}

__global__ __launch_bounds__(256) void scatter_kernel(
    const int* __restrict__ ei, int* __restrict__ cur, int* __restrict__ elist)
{
    int j = blockIdx.x*blockDim.x + threadIdx.x;
    if (j < EE) {
        int pos = atomicAdd(&cur[ei[EE + j]], 1);
        elist[pos] = j;
    }
}

// ---------------- Fused attention: w_qe trick + CSR walk, one wave per node ----------------
// alpha[j,h] = q[dst,h]·k[src,h] + ea[j,:]·w_qe[dst,h,:],  w_qe[n,h,k] = sum_d We[k,h*32+d] q[n,h*32+d]
// out[n,d] = (sum_j a_h v[src,d] + sum_k s[h][k] We[k,d]) / (den_h + 1e-16), s[h][k] = sum_j a_h ea[j,k]
__global__ __launch_bounds__(256) void fused_attn_kernel(
    const int* __restrict__ ei, const int* __restrict__ off, const int* __restrict__ elist,
    const float* __restrict__ ea, const float* __restrict__ q,
    const float* __restrict__ kmat, const float* __restrict__ vmat,
    const float* __restrict__ We, float* __restrict__ oa)
{
    __shared__ float lds[4][640];   // per wave: [0..127] q stage, [128..639] s stage
    const int w = threadIdx.x >> 6;
    const int l = threadIdx.x & 63;
    const int n = blockIdx.x*4 + w;
    if (n >= NN) return;
    float* qs = &lds[w][0];
    float* ss = &lds[w][128];
    const int hsel = l >> 5;        // head of col l; head of col 64+l is 2+hsel

    float q0 = q[(size_t)n*CD + l];
    float q1 = q[(size_t)n*CD + 64 + l];
    qs[l] = q0;
    qs[64 + l] = q1;                // same-wave LDS RAW: in-order LDS + compiler lgkmcnt

    // w_qe: lane owns k-rows l and 64+l of We
    const float* Wr0 = We + (size_t)l*CD;
    const float* Wr1 = We + (size_t)(64+l)*CD;
    float wq[4][2];
    #pragma unroll
    for (int h = 0; h < 4; ++h) {
        float a0 = 0.f, a1 = 0.f;
        #pragma unroll
        for (int d4 = 0; d4 < 8; ++d4) {
            float4 qv = *(float4*)&qs[h*32 + d4*4];   // broadcast LDS read
            float4 w0 = ld4(&Wr0[h*32 + d4*4]);
            float4 w1 = ld4(&Wr1[h*32 + d4*4]);
            a0 += w0.x*qv.x + w0.y*qv.y + w0.z*qv.z + w0.w*qv.w;
            a1 += w1.x*qv.x + w1.y*qv.y + w1.z*qv.z + w1.w*qv.w;
        }
        wq[h][0] = a0; wq[h][1] = a1;
    }

    const int beg = off[n], end = off[n+1];
    const float inv_sqrt_o = 0.17677669529663687f;  // 1/sqrt(32)
    float s00=0,s01=0,s10=0,s11=0,s20=0,s21=0,s30=0,s31=0;
    float av0=0, av1=0, den0=0, den1=0;
    for (int t = beg; t < end; ++t) {
        int eid = elist[t];
        int src = ei[eid];
        float ea0 = ea[(size_t)eid*CD + l];
        float ea1 = ea[(size_t)eid*CD + 64 + l];
        float k0  = kmat[(size_t)src*CD + l];
        float k1  = kmat[(size_t)src*CD + 64 + l];
        float v0  = vmat[(size_t)src*CD + l];
        float v1  = vmat[(size_t)src*CD + 64 + l];
        float p0 = ea0*wq[0][0] + ea1*wq[0][1];
        float p1 = ea0*wq[1][0] + ea1*wq[1][1];
        float p2 = ea0*wq[2][0] + ea1*wq[2][1];
        float p3 = ea0*wq[3][0] + ea1*wq[3][1];
        float qkL = q0*k0;   // contributes to head hsel
        float qkH = q1*k1;   // contributes to head 2+hsel
        if (hsel == 0) { p0 += qkL; p2 += qkH; }
        else           { p1 += qkL; p3 += qkH; }
        #pragma unroll
        for (int o = 32; o; o >>= 1) {
            p0 += __shfl_xor(p0, o);
            p1 += __shfl_xor(p1, o);
            p2 += __shfl_xor(p2, o);
            p3 += __shfl_xor(p3, o);
        }
        float aH0 = expf(p0 * inv_sqrt_o);
        float aH1 = expf(p1 * inv_sqrt_o);
        float aH2 = expf(p2 * inv_sqrt_o);
        float aH3 = expf(p3 * inv_sqrt_o);
        s00 += aH0*ea0; s01 += aH0*ea1;
        s10 += aH1*ea0; s11 += aH1*ea1;
        s20 += aH2*ea0; s21 += aH2*ea1;
        s30 += aH3*ea0; s31 += aH3*ea1;
        float aL = hsel ? aH1 : aH0;
        float aH = hsel ? aH3 : aH2;
        av0 += aL*v0; av1 += aH*v1;
        den0 += aL;   den1 += aH;
    }

    // s -> LDS, then GEMV through We (coalesced We reads)
    ss[0*128 + l] = s00;  ss[0*128 + 64 + l] = s01;
    ss[1*128 + l] = s10;  ss[1*128 + 64 + l] = s11;
    ss[2*128 + l] = s20;  ss[2*128 + 64 + l] = s21;
    ss[3*128 + l] = s30;  ss[3*128 + 64 + l] = s31;
    const float* sh0 = &ss[hsel*128];
    const float* sh1 = &ss[(2+hsel)*128];
    float oe0 = 0.f, oe1 = 0.f;
    #pragma unroll 4
    for (int k = 0; k < 128; ++k) {
        oe0 += sh0[k] * We[k*CD + l];
        oe1 += sh1[k] * We[k*CD + 64 + l];
    }
    oa[(size_t)n*CD + l]      = (av0 + oe0) / (den0 + 1e-16f);
    oa[(size_t)n*CD + 64 + l] = (av1 + oe1) / (den1 + 1e-16f);
}

// ---------------- combine: beta-gate, residual, LN1 stats (oa pre-normalized) ----------------
__global__ __launch_bounds__(256) void combine_kernel(
    const float* __restrict__ x, const float* __restrict__ xr,
    const float* __restrict__ oa,
    const float* __restrict__ Wbeta, float* __restrict__ y, double* __restrict__ red)
{
    const int lane = threadIdx.x & 63;
    const int wid = blockIdx.x*4 + (threadIdx.x >> 6);
    const int nw = gridDim.x*4;
    const int c0 = lane, c1 = lane + 64;
    const float wb_o0 = Wbeta[c0],     wb_o1 = Wbeta[c1];
    const float wb_x0 = Wbeta[128+c0], wb_x1 = Wbeta[128+c1];
    const float wb_d0 = Wbeta[256+c0], wb_d1 = Wbeta[256+c1];
    float lsum = 0.f, lsq = 0.f;
    for (int n = wid; n < NN; n += nw) {
        float o0 = oa[n*CD+c0];
        float o1 = oa[n*CD+c1];
        float r0v = xr[n*CD+c0], r1v = xr[n*CD+c1];
        float d = o0*wb_o0 + r0v*wb_x0 + (o0-r0v)*wb_d0
                + o1*wb_o1 + r1v*wb_x1 + (o1-r1v)*wb_d1;
        #pragma unroll
        for (int off = 32; off; off >>= 1) d += __shfl_xor(d, off);
        float beta = 1.0f / (1.0f + expf(-d));
        float y0 = x[n*CD+c0] + beta*r0v + (1.0f-beta)*o0;
        float y1 = x[n*CD+c1] + beta*r1v + (1.0f-beta)*o1;
        y[n*CD+c0] = y0; y[n*CD+c1] = y1;
        lsum += y0 + y1; lsq += y0*y0 + y1*y1;
    }
    #pragma unroll
    for (int off = 32; off; off >>= 1) {
        lsum += __shfl_xor(lsum, off);
        lsq  += __shfl_xor(lsq,  off);
    }
    if (lane == 0) {
        atomicAdd(&red[0], (double)lsum);
        atomicAdd(&red[1], (double)lsq);
    }
}

// ---------------- FFN1: LN1(y) @ W1 + bf1, exact gelu -> h ----------------
__global__ __launch_bounds__(256) void ffn1_gemm(
    const float* __restrict__ y, const float* __restrict__ W1, const float* __restrict__ bf1,
    const float* __restrict__ lng, const float* __restrict__ lnb,
    const double* __restrict__ red, float* __restrict__ h)
{
    __shared__ float ast[32*132];
    __shared__ float bst[32*132];
    const int tid = threadIdx.x;
    const int r0 = blockIdx.x * 128;
    const int cb = blockIdx.y;
    double m = red[0] * (1.0/NCF);
    double var = red[1] * (1.0/NCF) - m*m;
    if (var < 0.0) var = 0.0;
    const float mean = (float)m;
    const float scale = (float)(1.0 / (sqrt(var) + 1e-5));
    const int tc = tid & 15, tr = tid >> 4;
    float acc[8][8];
    #pragma unroll
    for (int i = 0; i < 8; ++i)
        #pragma unroll
        for (int j = 0; j < 8; ++j) acc[i][j] = 0.f;

    for (int kc = 0; kc < 4; ++kc) {
        #pragma unroll
        for (int it = 0; it < 4; ++it) {
            int chunk = it*256 + tid;
            int row = chunk >> 3, c4 = chunk & 7;
            float4 g = make_float4(0.f,0.f,0.f,0.f);
            if (r0 + row < NN) g = ld4(&y[(r0+row)*CD + kc*32 + c4*4]);
            int col = kc*32 + c4*4;
            g.x = (g.x - mean)*scale*lng[col+0] + lnb[col+0];
            g.y = (g.y - mean)*scale*lng[col+1] + lnb[col+1];
            g.z = (g.z - mean)*scale*lng[col+2] + lnb[col+2];
            g.w = (g.w - mean)*scale*lng[col+3] + lnb[col+3];
            ast[(c4*4+0)*132 + row] = g.x;
            ast[(c4*4+1)*132 + row] = g.y;
            ast[(c4*4+2)*132 + row] = g.z;
            ast[(c4*4+3)*132 + row] = g.w;
        }
        #pragma unroll
        for (int it = 0; it < 4; ++it) {
            int chunk = it*256 + tid;
            int kr = chunk >> 5, c4 = chunk & 31;
            *(float4*)&bst[kr*132 + c4*4] = ld4(&W1[(size_t)(kc*32+kr)*FD + cb*128 + c4*4]);
        }
        __syncthreads();
        #pragma unroll
        for (int k = 0; k < 32; ++k) {
            float4 a0 = *(float4*)&ast[k*132 + tr*8];
            float4 a1 = *(float4*)&ast[k*132 + tr*8 + 4];
            float4 b0 = *(float4*)&bst[k*132 + tc*8];
            float4 b1 = *(float4*)&bst[k*132 + tc*8 + 4];
            float ar[8] = {a0.x,a0.y,a0.z,a0.w,a1.x,a1.y,a1.z,a1.w};
            float br[8] = {b0.x,b0.y,b0.z,b0.w,b1.x,b1.y,b1.z,b1.w};
            #pragma unroll
            for (int i = 0; i < 8; ++i)
                #pragma unroll
                for (int j = 0; j < 8; ++j)
                    acc[i][j] += ar[i]*br[j];
        }
        __syncthreads();
    }
    float bcol[8];
    #pragma unroll
    for (int j = 0; j < 8; ++j) bcol[j] = bf1[cb*128 + tc*8 + j];
    #pragma unroll
    for (int i = 0; i < 8; ++i) {
        int row = r0 + tr*8 + i;
        if (row < NN) {
            float o[8];
            #pragma unroll
            for (int j = 0; j < 8; ++j) {
                float hv = acc[i][j] + bcol[j];
                o[j] = 0.5f*hv*(1.0f + erff(hv*0.7071067811865476f));
            }
            float4 o0 = make_float4(o[0],o[1],o[2],o[3]);
            float4 o1 = make_float4(o[4],o[5],o[6],o[7]);
            *(float4*)&h[(size_t)row*FD + cb*128 + tc*8]     = o0;
            *(float4*)&h[(size_t)row*FD + cb*128 + tc*8 + 4] = o1;
        }
    }
}

// ---------------- FFN2: h @ W2 + bf2 + LN1(y), LN2 stats -> d_out ----------------
__global__ __launch_bounds__(256) void ffn2_gemm(
    const float* __restrict__ h, const float* __restrict__ W2, const float* __restrict__ bf2,
    const float* __restrict__ y, const float* __restrict__ lng, const float* __restrict__ lnb,
    double* __restrict__ red, float* __restrict__ outz)
{
    __shared__ float ast[32*132];
    __shared__ float bst[32*132];
    const int tid = threadIdx.x;
    const int r0 = blockIdx.x * 128;
    double m = red[0] * (1.0/NCF);
    double var = red[1] * (1.0/NCF) - m*m;
    if (var < 0.0) var = 0.0;
    const float mean = (float)m;
    const float scale = (float)(1.0 / (sqrt(var) + 1e-5));
    const int tc = tid & 15, tr = tid >> 4;
    float acc[8][8];
    #pragma unroll
    for (int i = 0; i < 8; ++i)
        #pragma unroll
        for (int j = 0; j < 8; ++j) acc[i][j] = 0.f;

    for (int kc = 0; kc < 16; ++kc) {
        #pragma unroll
        for (int it = 0; it < 4; ++it) {
            int chunk = it*256 + tid;
            int row = chunk >> 3, c4 = chunk & 7;
            float4 g = make_float4(0.f,0.f,0.f,0.f);
            if (r0 + row < NN) g = ld4(&h[(size_t)(r0+row)*FD + kc*32 + c4*4]);
            ast[(c4*4+0)*132 + row] = g.x;
            ast[(c4*4+1)*132 + row] = g.y;
            ast[(c4*4+2)*132 + row] = g.z;
            ast[(c4*4+3)*132 + row] = g.w;
        }
        #pragma unroll
        for (int it = 0; it < 4; ++it) {
            int chunk = it*256 + tid;
            int kr = chunk >> 5, c4 = chunk & 31;
            *(float4*)&bst[kr*132 + c4*4] = ld4(&W2[(size_t)(kc*32+kr)*CD + c4*4]);
        }
        __syncthreads();
        #pragma unroll
        for (int k = 0; k < 32; ++k) {
            float4 a0 = *(float4*)&ast[k*132 + tr*8];
            float4 a1 = *(float4*)&ast[k*132 + tr*8 + 4];
            float4 b0 = *(float4*)&bst[k*132 + tc*8];
            float4 b1 = *(float4*)&bst[k*132 + tc*8 + 4];
            float ar[8] = {a0.x,a0.y,a0.z,a0.w,a1.x,a1.y,a1.z,a1.w};
            float br[8] = {b0.x,b0.y,b0.z,b0.w,b1.x,b1.y,b1.z,b1.w};
            #pragma unroll
            for (int i = 0; i < 8; ++i)
                #pragma unroll
                for (int j = 0; j < 8; ++j)
                    acc[i][j] += ar[i]*br[j];
        }
        __syncthreads();
    }
    float g1c[8], b1c[8], bfc[8];
    #pragma unroll
    for (int j = 0; j < 8; ++j) {
        int col = tc*8 + j;
        g1c[j] = lng[col]; b1c[j] = lnb[col]; bfc[j] = bf2[col];
    }
    float lsum = 0.f, lsq = 0.f;
    #pragma unroll
    for (int i = 0; i < 8; ++i) {
        int row = r0 + tr*8 + i;
        if (row < NN) {
            float4 ya = ld4(&y[row*CD + tc*8]);
            float4 yb = ld4(&y[row*CD + tc*8 + 4]);
            float yv[8] = {ya.x,ya.y,ya.z,ya.w,yb.x,yb.y,yb.z,yb.w};
            float z[8];
            #pragma unroll
            for (int j = 0; j < 8; ++j) {
                float x1 = (yv[j] - mean)*scale*g1c[j] + b1c[j];
                z[j] = acc[i][j] + bfc[j] + x1;
                lsum += z[j]; lsq += z[j]*z[j];
            }
            float4 z0 = make_float4(z[0],z[1],z[2],z[3]);
            float4 z1 = make_float4(z[4],z[5],z[6],z[7]);
            *(float4*)&outz[row*CD + tc*8]     = z0;
            *(float4*)&outz[row*CD + tc*8 + 4] = z1;
        }
    }
    #pragma unroll
    for (int off = 32; off; off >>= 1) {
        lsum += __shfl_xor(lsum, off);
        lsq  += __shfl_xor(lsq,  off);
    }
    if ((threadIdx.x & 63) == 0) {
        atomicAdd(&red[2], (double)lsum);
        atomicAdd(&red[3], (double)lsq);
    }
}

// ---------------- LN2 in-place on d_out ----------------
__global__ __launch_bounds__(256) void ln2_kernel(
    float* __restrict__ z, const float* __restrict__ g2, const float* __restrict__ b2,
    const double* __restrict__ red)
{
    double m = red[2] * (1.0/NCF);
    double var = red[3] * (1.0/NCF) - m*m;
    if (var < 0.0) var = 0.0;
    const float mean = (float)m;
    const float scale = (float)(1.0 / (sqrt(var) + 1e-5));
    const int stride = gridDim.x * blockDim.x;
    for (int i = blockIdx.x*blockDim.x + threadIdx.x; i < NN*32; i += stride) {
        int c4 = (i & 31) * 4;
        float4 zv = *(float4*)&z[(size_t)i*4];
        float4 gv = ld4(&g2[c4]);
        float4 bv = ld4(&b2[c4]);
        zv.x = (zv.x - mean)*scale*gv.x + bv.x;
        zv.y = (zv.y - mean)*scale*gv.y + bv.y;
        zv.z = (zv.z - mean)*scale*gv.z + bv.z;
        zv.w = (zv.w - mean)*scale*gv.w + bv.w;
        *(float4*)&z[(size_t)i*4] = zv;
    }
}

extern "C" void kernel_launch(void* const* d_in, const int* in_sizes, int n_in,
                              void* d_out, int out_size, void* d_ws, size_t ws_size,
                              hipStream_t stream) {
    const float* x     = (const float*)d_in[0];
    const float* ea    = (const float*)d_in[1];
    const int*   ei    = (const int*)d_in[2];      // integers arrive as int32
    const float* Wq    = (const float*)d_in[3];
    const float* bq    = (const float*)d_in[4];
    const float* Wk    = (const float*)d_in[5];
    const float* bk    = (const float*)d_in[6];
    const float* Wv    = (const float*)d_in[7];
    const float* bv    = (const float*)d_in[8];
    const float* We    = (const float*)d_in[9];
    const float* Wsk   = (const float*)d_in[10];
    const float* bsk   = (const float*)d_in[11];
    const float* Wbeta = (const float*)d_in[12];
    const float* g1v   = (const float*)d_in[13];
    const float* be1   = (const float*)d_in[14];
    const float* g2v   = (const float*)d_in[15];
    const float* be2   = (const float*)d_in[16];
    const float* W1    = (const float*)d_in[17];
    const float* bf1   = (const float*)d_in[18];
    const float* W2    = (const float*)d_in[19];
    const float* bf2   = (const float*)d_in[20];

    float* wsf = (float*)d_ws;
    float* q    = wsf;                  // dead after fused_attn; reused as y
    float* kk   = wsf +  6400000;       // dead after fused_attn; h[0]
    float* vv   = wsf + 12800000;       // dead after fused_attn; h[1]
    float* xr   = wsf + 19200000;       // dead after combine; h[2]
    float* oa   = wsf + 25600000;       // dead after combine; h[3]
    int*   off  = (int*)(wsf + 34400000);  // 50001 ints
    int*   cur  = off + 50001;             // 50000 ints (histogram -> scatter cursor)
    int*   elist= cur + 50000;             // 600000 ints
    double* red = (double*)(wsf + 35100056); // 8B-aligned
    float* y = q;
    float* h = kk;                      // h spans [6.4M, 32.0M) = N*512 floats
    float* zout = (float*)d_out;

    (void)hipMemsetAsync(cur, 0, 50000*sizeof(int), stream);
    (void)hipMemsetAsync(red, 0, 4*sizeof(double), stream);

    // CSR build
    hist_kernel<<<(EE+255)/256, 256, 0, stream>>>(ei, cur);
    scan_kernel<<<1, 256, 0, stream>>>(cur, off);
    scatter_kernel<<<(EE+255)/256, 256, 0, stream>>>(ei, cur, elist);

    dim3 gA((NN + 127)/128, 4);
    qkvs_gemm<<<gA, 256, 0, stream>>>(x, Wq,bq, Wk,bk, Wv,bv, Wsk,bsk, q, kk, vv, xr);

    fused_attn_kernel<<<(NN + 3)/4, 256, 0, stream>>>(ei, off, elist, ea, q, kk, vv, We, oa);

    combine_kernel<<<1024, 256, 0, stream>>>(x, xr, oa, Wbeta, y, red);

    dim3 gF((NN + 127)/128, 4);
    ffn1_gemm<<<gF, 256, 0, stream>>>(y, W1, bf1, g1v, be1, red, h);

    ffn2_gemm<<<(NN + 127)/128, 256, 0, stream>>>(h, W2, bf2, y, g1v, be1, red, zout);

    ln2_kernel<<<2048, 256, 0, stream>>>(zout, g2v, be2, red);
}

// Round 9
// 1801.997 us; speedup vs baseline: 1.0729x; 1.0729x over previous
//
#include <hip/hip_runtime.h>
#include <math.h>

#define NN 50000
#define EE 600000
#define CD 128
#define FD 512
#define NCF 6400000.0   // NN*CD as double

__device__ __forceinline__ float4 ld4(const float* p){ return *(const float4*)p; }

// ---------------- GEMM: q,k,v,skip = x @ {Wq,Wk,Wv,Wskip} + bias ----------------
__global__ __launch_bounds__(256) void qkvs_gemm(
    const float* __restrict__ x,
    const float* __restrict__ Wq, const float* __restrict__ bq,
    const float* __restrict__ Wk, const float* __restrict__ bk,
    const float* __restrict__ Wv, const float* __restrict__ bv,
    const float* __restrict__ Wsk, const float* __restrict__ bsk,
    float* __restrict__ oq, float* __restrict__ okk,
    float* __restrict__ ov, float* __restrict__ osk)
{
    __shared__ float ast[32*132];
    __shared__ float bst[32*132];
    const int tid = threadIdx.x;
    const int r0 = blockIdx.x * 128;
    const float* W; const float* bias; float* out;
    switch (blockIdx.y) {
        case 0:  W = Wq;  bias = bq;  out = oq;  break;
        case 1:  W = Wk;  bias = bk;  out = okk; break;
        case 2:  W = Wv;  bias = bv;  out = ov;  break;
        default: W = Wsk; bias = bsk; out = osk; break;
    }
    const int tc = tid & 15, tr = tid >> 4;
    float acc[8][8];
    #pragma unroll
    for (int i = 0; i < 8; ++i)
        #pragma unroll
        for (int j = 0; j < 8; ++j) acc[i][j] = 0.f;

    for (int kc = 0; kc < 4; ++kc) {
        #pragma unroll
        for (int it = 0; it < 4; ++it) {
            int chunk = it*256 + tid;
            int row = chunk >> 3, c4 = chunk & 7;
            float4 g = make_float4(0.f,0.f,0.f,0.f);
            if (r0 + row < NN) g = ld4(&x[(r0+row)*CD + kc*32 + c4*4]);
            ast[(c4*4+0)*132 + row] = g.x;
            ast[(c4*4+1)*132 + row] = g.y;
            ast[(c4*4+2)*132 + row] = g.z;
            ast[(c4*4+3)*132 + row] = g.w;
        }
        #pragma unroll
        for (int it = 0; it < 4; ++it) {
            int chunk = it*256 + tid;
            int kr = chunk >> 5, c4 = chunk & 31;
            *(float4*)&bst[kr*132 + c4*4] = ld4(&W[(kc*32+kr)*CD + c4*4]);
        }
        __syncthreads();
        #pragma unroll
        for (int k = 0; k < 32; ++k) {
            float4 a0 = *(float4*)&ast[k*132 + tr*8];
            float4 a1 = *(float4*)&ast[k*132 + tr*8 + 4];
            float4 b0 = *(float4*)&bst[k*132 + tc*8];
            float4 b1 = *(float4*)&bst[k*132 + tc*8 + 4];
            float ar[8] = {a0.x,a0.y,a0.z,a0.w,a1.x,a1.y,a1.z,a1.w};
            float br[8] = {b0.x,b0.y,b0.z,b0.w,b1.x,b1.y,b1.z,b1.w};
            #pragma unroll
            for (int i = 0; i < 8; ++i)
                #pragma unroll
                for (int j = 0; j < 8; ++j)
                    acc[i][j] += ar[i]*br[j];
        }
        __syncthreads();
    }
    float bcol[8];
    #pragma unroll
    for (int j = 0; j < 8; ++j) bcol[j] = bias[tc*8+j];
    #pragma unroll
    for (int i = 0; i < 8; ++i) {
        int row = r0 + tr*8 + i;
        if (row < NN) {
            float4 o0 = make_float4(acc[i][0]+bcol[0], acc[i][1]+bcol[1],
                                    acc[i][2]+bcol[2], acc[i][3]+bcol[3]);
            float4 o1 = make_float4(acc[i][4]+bcol[4], acc[i][5]+bcol[5],
                                    acc[i][6]+bcol[6], acc[i][7]+bcol[7]);
            *(float4*)&out[row*CD + tc*8]     = o0;
            *(float4*)&out[row*CD + tc*8 + 4] = o1;
        }
    }
}

// ---------------- CSR build ----------------
__global__ __launch_bounds__(256) void hist_kernel(const int* __restrict__ ei, int* __restrict__ cnt)
{
    int j = blockIdx.x*blockDim.x + threadIdx.x;
    if (j < EE) atomicAdd(&cnt[ei[EE + j]], 1);
}

__global__ __launch_bounds__(256) void scan_kernel(int* __restrict__ cnt, int* __restrict__ off)
{
    __shared__ int part[256];
    const int t = threadIdx.x;
    const int nper = (NN + 255) / 256;
    const int lo = t*nper, hi = min(lo + nper, NN);
    int ssum = 0;
    for (int i = lo; i < hi; ++i) ssum += cnt[i];
    part[t] = ssum;
    __syncthreads();
    if (t == 0) {
        int run = 0;
        for (int i = 0; i < 256; ++i) { int tmp = part[i]; part[i] = run; run += tmp; }
    }
    __syncthreads();
    int run = part[t];
    for (int i = lo; i < hi; ++i) {
        int c = cnt[i];
        off[i] = run;
        cnt[i] = run;
        run += c;
    }
    if (hi == NN) off[NN] = run;
}

__global__ __launch_bounds__(256) void scatter_kernel(
    const int* __restrict__ ei, int* __restrict__ cur, int* __restrict__ elist)
{
    int j = blockIdx.x*blockDim.x + threadIdx.x;
    if (j < EE) {
        int pos = atomicAdd(&cur[ei[EE + j]], 1);
        elist[pos] = j;
    }
}

// ---------------- attn_score: per-node wave, w_qe in LDS, 4 lanes/edge ----------------
// alpha[j,h] = q[n,h]·k[src,h] + ea[j,:]·wqe[h,:];  wqe[h][k] = sum_d We[k][h*32+d] q[n][h*32+d]
// Writes a = exp(alpha/sqrt(32)) in CSR order: a4csr[pos*4 + h].
// LDS layout (per wave, padded 32->36 word chunks: conflict-free AND 16B-aligned):
//   qs:  idx(k) = (k>>5)*36 + (k&31)          [144 floats]
//   wqe: 144 + h*144 + idx(k)                 [576 floats]
__global__ __launch_bounds__(256) void attn_score_kernel(
    const int* __restrict__ ei, const int* __restrict__ off, const int* __restrict__ elist,
    const float* __restrict__ ea, const float* __restrict__ q,
    const float* __restrict__ kmat, const float* __restrict__ We,
    float* __restrict__ a4csr)
{
    __shared__ float lds[4][720];
    const int w = threadIdx.x >> 6;
    const int l = threadIdx.x & 63;
    const int n = blockIdx.x*4 + w;
    if (n >= NN) return;
    float* qs = &lds[w][0];
    float* wq = &lds[w][144];

    // phase 1: stage q[n]
    float q0 = q[(size_t)n*CD + l];
    float q1 = q[(size_t)n*CD + 64 + l];
    qs[(l>>5)*36 + (l&31)]       = q0;
    qs[(2+(l>>5))*36 + (l&31)]   = q1;

    // phase 2: wqe — lane l owns We rows l and 64+l (L1-resident)
    const float* Wr0 = We + (size_t)l*CD;
    const float* Wr1 = We + (size_t)(64+l)*CD;
    #pragma unroll
    for (int h = 0; h < 4; ++h) {
        float s0 = 0.f, s1 = 0.f;
        #pragma unroll
        for (int d4 = 0; d4 < 8; ++d4) {
            float4 qv = *(float4*)&qs[h*36 + d4*4];   // broadcast (same-wave RAW)
            float4 w0 = ld4(&Wr0[h*32 + d4*4]);
            float4 w1 = ld4(&Wr1[h*32 + d4*4]);
            s0 += w0.x*qv.x + w0.y*qv.y + w0.z*qv.z + w0.w*qv.w;
            s1 += w1.x*qv.x + w1.y*qv.y + w1.z*qv.z + w1.w*qv.w;
        }
        wq[h*144 + (l>>5)*36 + (l&31)]     = s0;   // k = l
        wq[h*144 + (2+(l>>5))*36 + (l&31)] = s1;   // k = 64+l
    }

    // phase 3: 16 edges/round, 4 lanes per edge (lane c owns dims [c*32, c*32+32) = head c)
    const int beg = off[n], end = off[n+1];
    const int slot = l >> 2, c = l & 3;
    const int nr = (end - beg + 15) >> 4;
    const float inv_sqrt_o = 0.17677669529663687f;  // 1/sqrt(32)
    for (int r = 0; r < nr; ++r) {
        int es = beg + r*16 + slot;
        bool act = es < end;
        float pe0=0.f, pe1=0.f, pe2=0.f, pe3=0.f, qk=0.f;
        if (act) {
            int eid = elist[es];
            int sn  = ei[eid];
            const float* eap = ea   + (size_t)eid*CD + c*32;
            const float* kp  = kmat + (size_t)sn*CD + c*32;
            #pragma unroll
            for (int d4 = 0; d4 < 8; ++d4) {
                float4 eav = ld4(eap + d4*4);
                float4 kv  = ld4(kp + d4*4);
                float4 qv  = *(float4*)&qs[c*36 + d4*4];
                float4 w0  = *(float4*)&wq[0*144 + c*36 + d4*4];
                float4 w1  = *(float4*)&wq[1*144 + c*36 + d4*4];
                float4 w2  = *(float4*)&wq[2*144 + c*36 + d4*4];
                float4 w3  = *(float4*)&wq[3*144 + c*36 + d4*4];
                pe0 += eav.x*w0.x + eav.y*w0.y + eav.z*w0.z + eav.w*w0.w;
                pe1 += eav.x*w1.x + eav.y*w1.y + eav.z*w1.z + eav.w*w1.w;
                pe2 += eav.x*w2.x + eav.y*w2.y + eav.z*w2.z + eav.w*w2.w;
                pe3 += eav.x*w3.x + eav.y*w3.y + eav.z*w3.z + eav.w*w3.w;
                qk  += qv.x*kv.x + qv.y*kv.y + qv.z*kv.z + qv.w*kv.w;
            }
        }
        // reduce ea·wqe partials over the 4 lanes of this edge (2 steps)
        pe0 += __shfl_xor(pe0, 1);  pe0 += __shfl_xor(pe0, 2);
        pe1 += __shfl_xor(pe1, 1);  pe1 += __shfl_xor(pe1, 2);
        pe2 += __shfl_xor(pe2, 1);  pe2 += __shfl_xor(pe2, 2);
        pe3 += __shfl_xor(pe3, 1);  pe3 += __shfl_xor(pe3, 2);
        float pe = (c==0) ? pe0 : (c==1) ? pe1 : (c==2) ? pe2 : pe3;
        if (act) a4csr[(size_t)es*4 + c] = expf((pe + qk) * inv_sqrt_o);
    }
}

// ---------------- Node kernel: per-dst aggregation, a in CSR order ----------------
__global__ __launch_bounds__(256) void node_kernel(
    const int* __restrict__ ei, const int* __restrict__ off, const int* __restrict__ elist,
    const float* __restrict__ a4csr, const float* __restrict__ ea,
    const float* __restrict__ vmat, const float* __restrict__ We,
    float* __restrict__ oa)
{
    __shared__ float s_lds[4][512];
    const int w = threadIdx.x >> 6;
    const int l = threadIdx.x & 63;
    const int n = blockIdx.x * 4 + w;
    if (n >= NN) return;
    const int beg = off[n], end = off[n+1];
    const int hsel = l >> 5;
    float s0k0=0,s1k0=0,s2k0=0,s3k0=0;
    float s0k1=0,s1k1=0,s2k1=0,s3k1=0;
    float av0=0, av1=0, den0=0, den1=0;
    for (int t = beg; t < end; ++t) {
        int eid = elist[t];
        int src = ei[eid];
        float4 aq = ld4(&a4csr[(size_t)t*4]);
        float ea0 = ea[(size_t)eid*CD + l];
        float ea1 = ea[(size_t)eid*CD + 64 + l];
        float v0  = vmat[(size_t)src*CD + l];
        float v1  = vmat[(size_t)src*CD + 64 + l];
        float aH0 = hsel ? aq.y : aq.x;
        float aH1 = hsel ? aq.w : aq.z;
        s0k0 += aq.x*ea0; s1k0 += aq.y*ea0; s2k0 += aq.z*ea0; s3k0 += aq.w*ea0;
        s0k1 += aq.x*ea1; s1k1 += aq.y*ea1; s2k1 += aq.z*ea1; s3k1 += aq.w*ea1;
        av0 += aH0*v0; av1 += aH1*v1;
        den0 += aH0;   den1 += aH1;
    }
    s_lds[w][0*128 + l] = s0k0;  s_lds[w][0*128 + 64 + l] = s0k1;
    s_lds[w][1*128 + l] = s1k0;  s_lds[w][1*128 + 64 + l] = s1k1;
    s_lds[w][2*128 + l] = s2k0;  s_lds[w][2*128 + 64 + l] = s2k1;
    s_lds[w][3*128 + l] = s3k0;  s_lds[w][3*128 + 64 + l] = s3k1;
    const float* sh0 = &s_lds[w][hsel*128];
    const float* sh1 = &s_lds[w][(2+hsel)*128];
    float oe0 = 0.f, oe1 = 0.f;
    #pragma unroll 4
    for (int k = 0; k < 128; ++k) {
        oe0 += sh0[k] * We[k*CD + l];
        oe1 += sh1[k] * We[k*CD + 64 + l];
    }
    oa[(size_t)n*CD + l]      = (av0 + oe0) / (den0 + 1e-16f);
    oa[(size_t)n*CD + 64 + l] = (av1 + oe1) / (den1 + 1e-16f);
}

// ---------------- combine: beta-gate, residual, LN1 stats ----------------
__global__ __launch_bounds__(256) void combine_kernel(
    const float* __restrict__ x, const float* __restrict__ xr,
    const float* __restrict__ oa,
    const float* __restrict__ Wbeta, float* __restrict__ y, double* __restrict__ red)
{
    const int lane = threadIdx.x & 63;
    const int wid = blockIdx.x*4 + (threadIdx.x >> 6);
    const int nw = gridDim.x*4;
    const int c0 = lane, c1 = lane + 64;
    const float wb_o0 = Wbeta[c0],     wb_o1 = Wbeta[c1];
    const float wb_x0 = Wbeta[128+c0], wb_x1 = Wbeta[128+c1];
    const float wb_d0 = Wbeta[256+c0], wb_d1 = Wbeta[256+c1];
    float lsum = 0.f, lsq = 0.f;
    for (int n = wid; n < NN; n += nw) {
        float o0 = oa[n*CD+c0];
        float o1 = oa[n*CD+c1];
        float r0v = xr[n*CD+c0], r1v = xr[n*CD+c1];
        float d = o0*wb_o0 + r0v*wb_x0 + (o0-r0v)*wb_d0
                + o1*wb_o1 + r1v*wb_x1 + (o1-r1v)*wb_d1;
        #pragma unroll
        for (int off = 32; off; off >>= 1) d += __shfl_xor(d, off);
        float beta = 1.0f / (1.0f + expf(-d));
        float y0 = x[n*CD+c0] + beta*r0v + (1.0f-beta)*o0;
        float y1 = x[n*CD+c1] + beta*r1v + (1.0f-beta)*o1;
        y[n*CD+c0] = y0; y[n*CD+c1] = y1;
        lsum += y0 + y1; lsq += y0*y0 + y1*y1;
    }
    #pragma unroll
    for (int off = 32; off; off >>= 1) {
        lsum += __shfl_xor(lsum, off);
        lsq  += __shfl_xor(lsq,  off);
    }
    if (lane == 0) {
        atomicAdd(&red[0], (double)lsum);
        atomicAdd(&red[1], (double)lsq);
    }
}

// ---------------- FFN1: LN1(y) @ W1 + bf1, exact gelu -> h ----------------
__global__ __launch_bounds__(256) void ffn1_gemm(
    const float* __restrict__ y, const float* __restrict__ W1, const float* __restrict__ bf1,
    const float* __restrict__ lng, const float* __restrict__ lnb,
    const double* __restrict__ red, float* __restrict__ h)
{
    __shared__ float ast[32*132];
    __shared__ float bst[32*132];
    const int tid = threadIdx.x;
    const int r0 = blockIdx.x * 128;
    const int cb = blockIdx.y;
    double m = red[0] * (1.0/NCF);
    double var = red[1] * (1.0/NCF) - m*m;
    if (var < 0.0) var = 0.0;
    const float mean = (float)m;
    const float scale = (float)(1.0 / (sqrt(var) + 1e-5));
    const int tc = tid & 15, tr = tid >> 4;
    float acc[8][8];
    #pragma unroll
    for (int i = 0; i < 8; ++i)
        #pragma unroll
        for (int j = 0; j < 8; ++j) acc[i][j] = 0.f;

    for (int kc = 0; kc < 4; ++kc) {
        #pragma unroll
        for (int it = 0; it < 4; ++it) {
            int chunk = it*256 + tid;
            int row = chunk >> 3, c4 = chunk & 7;
            float4 g = make_float4(0.f,0.f,0.f,0.f);
            if (r0 + row < NN) g = ld4(&y[(r0+row)*CD + kc*32 + c4*4]);
            int col = kc*32 + c4*4;
            g.x = (g.x - mean)*scale*lng[col+0] + lnb[col+0];
            g.y = (g.y - mean)*scale*lng[col+1] + lnb[col+1];
            g.z = (g.z - mean)*scale*lng[col+2] + lnb[col+2];
            g.w = (g.w - mean)*scale*lng[col+3] + lnb[col+3];
            ast[(c4*4+0)*132 + row] = g.x;
            ast[(c4*4+1)*132 + row] = g.y;
            ast[(c4*4+2)*132 + row] = g.z;
            ast[(c4*4+3)*132 + row] = g.w;
        }
        #pragma unroll
        for (int it = 0; it < 4; ++it) {
            int chunk = it*256 + tid;
            int kr = chunk >> 5, c4 = chunk & 31;
            *(float4*)&bst[kr*132 + c4*4] = ld4(&W1[(size_t)(kc*32+kr)*FD + cb*128 + c4*4]);
        }
        __syncthreads();
        #pragma unroll
        for (int k = 0; k < 32; ++k) {
            float4 a0 = *(float4*)&ast[k*132 + tr*8];
            float4 a1 = *(float4*)&ast[k*132 + tr*8 + 4];
            float4 b0 = *(float4*)&bst[k*132 + tc*8];
            float4 b1 = *(float4*)&bst[k*132 + tc*8 + 4];
            float ar[8] = {a0.x,a0.y,a0.z,a0.w,a1.x,a1.y,a1.z,a1.w};
            float br[8] = {b0.x,b0.y,b0.z,b0.w,b1.x,b1.y,b1.z,b1.w};
            #pragma unroll
            for (int i = 0; i < 8; ++i)
                #pragma unroll
                for (int j = 0; j < 8; ++j)
                    acc[i][j] += ar[i]*br[j];
        }
        __syncthreads();
    }
    float bcol[8];
    #pragma unroll
    for (int j = 0; j < 8; ++j) bcol[j] = bf1[cb*128 + tc*8 + j];
    #pragma unroll
    for (int i = 0; i < 8; ++i) {
        int row = r0 + tr*8 + i;
        if (row < NN) {
            float o[8];
            #pragma unroll
            for (int j = 0; j < 8; ++j) {
                float hv = acc[i][j] + bcol[j];
                o[j] = 0.5f*hv*(1.0f + erff(hv*0.7071067811865476f));
            }
            float4 o0 = make_float4(o[0],o[1],o[2],o[3]);
            float4 o1 = make_float4(o[4],o[5],o[6],o[7]);
            *(float4*)&h[(size_t)row*FD + cb*128 + tc*8]     = o0;
            *(float4*)&h[(size_t)row*FD + cb*128 + tc*8 + 4] = o1;
        }
    }
}

// ---------------- FFN2: h @ W2 + bf2 + LN1(y), LN2 stats -> d_out ----------------
__global__ __launch_bounds__(256) void ffn2_gemm(
    const float* __restrict__ h, const float* __restrict__ W2, const float* __restrict__ bf2,
    const float* __restrict__ y, const float* __restrict__ lng, const float* __restrict__ lnb,
    double* __restrict__ red, float* __restrict__ outz)
{
    __shared__ float ast[32*132];
    __shared__ float bst[32*132];
    const int tid = threadIdx.x;
    const int r0 = blockIdx.x * 128;
    double m = red[0] * (1.0/NCF);
    double var = red[1] * (1.0/NCF) - m*m;
    if (var < 0.0) var = 0.0;
    const float mean = (float)m;
    const float scale = (float)(1.0 / (sqrt(var) + 1e-5));
    const int tc = tid & 15, tr = tid >> 4;
    float acc[8][8];
    #pragma unroll
    for (int i = 0; i < 8; ++i)
        #pragma unroll
        for (int j = 0; j < 8; ++j) acc[i][j] = 0.f;

    for (int kc = 0; kc < 16; ++kc) {
        #pragma unroll
        for (int it = 0; it < 4; ++it) {
            int chunk = it*256 + tid;
            int row = chunk >> 3, c4 = chunk & 7;
            float4 g = make_float4(0.f,0.f,0.f,0.f);
            if (r0 + row < NN) g = ld4(&h[(size_t)(r0+row)*FD + kc*32 + c4*4]);
            ast[(c4*4+0)*132 + row] = g.x;
            ast[(c4*4+1)*132 + row] = g.y;
            ast[(c4*4+2)*132 + row] = g.z;
            ast[(c4*4+3)*132 + row] = g.w;
        }
        #pragma unroll
        for (int it = 0; it < 4; ++it) {
            int chunk = it*256 + tid;
            int kr = chunk >> 5, c4 = chunk & 31;
            *(float4*)&bst[kr*132 + c4*4] = ld4(&W2[(size_t)(kc*32+kr)*CD + c4*4]);
        }
        __syncthreads();
        #pragma unroll
        for (int k = 0; k < 32; ++k) {
            float4 a0 = *(float4*)&ast[k*132 + tr*8];
            float4 a1 = *(float4*)&ast[k*132 + tr*8 + 4];
            float4 b0 = *(float4*)&bst[k*132 + tc*8];
            float4 b1 = *(float4*)&bst[k*132 + tc*8 + 4];
            float ar[8] = {a0.x,a0.y,a0.z,a0.w,a1.x,a1.y,a1.z,a1.w};
            float br[8] = {b0.x,b0.y,b0.z,b0.w,b1.x,b1.y,b1.z,b1.w};
            #pragma unroll
            for (int i = 0; i < 8; ++i)
                #pragma unroll
                for (int j = 0; j < 8; ++j)
                    acc[i][j] += ar[i]*br[j];
        }
        __syncthreads();
    }
    float g1c[8], b1c[8], bfc[8];
    #pragma unroll
    for (int j = 0; j < 8; ++j) {
        int col = tc*8 + j;
        g1c[j] = lng[col]; b1c[j] = lnb[col]; bfc[j] = bf2[col];
    }
    float lsum = 0.f, lsq = 0.f;
    #pragma unroll
    for (int i = 0; i < 8; ++i) {
        int row = r0 + tr*8 + i;
        if (row < NN) {
            float4 ya = ld4(&y[row*CD + tc*8]);
            float4 yb = ld4(&y[row*CD + tc*8 + 4]);
            float yv[8] = {ya.x,ya.y,ya.z,ya.w,yb.x,yb.y,yb.z,yb.w};
            float z[8];
            #pragma unroll
            for (int j = 0; j < 8; ++j) {
                float x1 = (yv[j] - mean)*scale*g1c[j] + b1c[j];
                z[j] = acc[i][j] + bfc[j] + x1;
                lsum += z[j]; lsq += z[j]*z[j];
            }
            float4 z0 = make_float4(z[0],z[1],z[2],z[3]);
            float4 z1 = make_float4(z[4],z[5],z[6],z[7]);
            *(float4*)&outz[row*CD + tc*8]     = z0;
            *(float4*)&outz[row*CD + tc*8 + 4] = z1;
        }
    }
    #pragma unroll
    for (int off = 32; off; off >>= 1) {
        lsum += __shfl_xor(lsum, off);
        lsq  += __shfl_xor(lsq,  off);
    }
    if ((threadIdx.x & 63) == 0) {
        atomicAdd(&red[2], (double)lsum);
        atomicAdd(&red[3], (double)lsq);
    }
}

// ---------------- LN2 in-place on d_out ----------------
__global__ __launch_bounds__(256) void ln2_kernel(
    float* __restrict__ z, const float* __restrict__ g2, const float* __restrict__ b2,
    const double* __restrict__ red)
{
    double m = red[2] * (1.0/NCF);
    double var = red[3] * (1.0/NCF) - m*m;
    if (var < 0.0) var = 0.0;
    const float mean = (float)m;
    const float scale = (float)(1.0 / (sqrt(var) + 1e-5));
    const int stride = gridDim.x * blockDim.x;
    for (int i = blockIdx.x*blockDim.x + threadIdx.x; i < NN*32; i += stride) {
        int c4 = (i & 31) * 4;
        float4 zv = *(float4*)&z[(size_t)i*4];
        float4 gv = ld4(&g2[c4]);
        float4 bv = ld4(&b2[c4]);
        zv.x = (zv.x - mean)*scale*gv.x + bv.x;
        zv.y = (zv.y - mean)*scale*gv.y + bv.y;
        zv.z = (zv.z - mean)*scale*gv.z + bv.z;
        zv.w = (zv.w - mean)*scale*gv.w + bv.w;
        *(float4*)&z[(size_t)i*4] = zv;
    }
}

extern "C" void kernel_launch(void* const* d_in, const int* in_sizes, int n_in,
                              void* d_out, int out_size, void* d_ws, size_t ws_size,
                              hipStream_t stream) {
    const float* x     = (const float*)d_in[0];
    const float* ea    = (const float*)d_in[1];
    const int*   ei    = (const int*)d_in[2];      // integers arrive as int32
    const float* Wq    = (const float*)d_in[3];
    const float* bq    = (const float*)d_in[4];
    const float* Wk    = (const float*)d_in[5];
    const float* bk    = (const float*)d_in[6];
    const float* Wv    = (const float*)d_in[7];
    const float* bv    = (const float*)d_in[8];
    const float* We    = (const float*)d_in[9];
    const float* Wsk   = (const float*)d_in[10];
    const float* bsk   = (const float*)d_in[11];
    const float* Wbeta = (const float*)d_in[12];
    const float* g1v   = (const float*)d_in[13];
    const float* be1   = (const float*)d_in[14];
    const float* g2v   = (const float*)d_in[15];
    const float* be2   = (const float*)d_in[16];
    const float* W1    = (const float*)d_in[17];
    const float* bf1   = (const float*)d_in[18];
    const float* W2    = (const float*)d_in[19];
    const float* bf2   = (const float*)d_in[20];

    float* wsf = (float*)d_ws;
    float* q    = wsf;                  // dead after attn_score; reused as y
    float* kk   = wsf +  6400000;       // dead after attn_score; h[0]
    float* vv   = wsf + 12800000;       // dead after node;  h[1]
    float* xr   = wsf + 19200000;       // dead after combine; h[2]
    float* oa   = wsf + 25600000;       // dead after combine; h[3]
    float* a4   = wsf + 32000000;       // per-edge exp scores, CSR order
    int*   off  = (int*)(wsf + 34400000);  // 50001 ints
    int*   cur  = off + 50001;             // 50000 ints
    int*   elist= cur + 50000;             // 600000 ints
    double* red = (double*)(wsf + 35100056); // 8B-aligned
    float* y = q;
    float* h = kk;                      // h spans [6.4M, 32.0M) = N*512 floats
    float* zout = (float*)d_out;

    (void)hipMemsetAsync(cur, 0, 50000*sizeof(int), stream);
    (void)hipMemsetAsync(red, 0, 4*sizeof(double), stream);

    // CSR build
    hist_kernel<<<(EE+255)/256, 256, 0, stream>>>(ei, cur);
    scan_kernel<<<1, 256, 0, stream>>>(cur, off);
    scatter_kernel<<<(EE+255)/256, 256, 0, stream>>>(ei, cur, elist);

    dim3 gA((NN + 127)/128, 4);
    qkvs_gemm<<<gA, 256, 0, stream>>>(x, Wq,bq, Wk,bk, Wv,bv, Wsk,bsk, q, kk, vv, xr);

    attn_score_kernel<<<(NN + 3)/4, 256, 0, stream>>>(ei, off, elist, ea, q, kk, We, a4);

    node_kernel<<<(NN + 3)/4, 256, 0, stream>>>(ei, off, elist, a4, ea, vv, We, oa);

    combine_kernel<<<1024, 256, 0, stream>>>(x, xr, oa, Wbeta, y, red);

    dim3 gF((NN + 127)/128, 4);
    ffn1_gemm<<<gF, 256, 0, stream>>>(y, W1, bf1, g1v, be1, red, h);

    ffn2_gemm<<<(NN + 127)/128, 256, 0, stream>>>(h, W2, bf2, y, g1v, be1, red, zout);

    ln2_kernel<<<2048, 256, 0, stream>>>(zout, g2v, be2, red);
}

// Round 10
// 1579.423 us; speedup vs baseline: 1.2241x; 1.1409x over previous
//
#include <hip/hip_runtime.h>
#include <math.h>

#define NN 50000
#define EE 600000
#define CD 128
#define FD 512
#define NCF 6400000.0   // NN*CD as double

__device__ __forceinline__ float4 ld4(const float* p){ return *(const float4*)p; }

// ---------------- GEMM: q,k,v,skip = x @ {Wq,Wk,Wv,Wskip} + bias ----------------
__global__ __launch_bounds__(256) void qkvs_gemm(
    const float* __restrict__ x,
    const float* __restrict__ Wq, const float* __restrict__ bq,
    const float* __restrict__ Wk, const float* __restrict__ bk,
    const float* __restrict__ Wv, const float* __restrict__ bv,
    const float* __restrict__ Wsk, const float* __restrict__ bsk,
    float* __restrict__ oq, float* __restrict__ okk,
    float* __restrict__ ov, float* __restrict__ osk)
{
    __shared__ float ast[32*132];
    __shared__ float bst[32*132];
    const int tid = threadIdx.x;
    const int r0 = blockIdx.x * 128;
    const float* W; const float* bias; float* out;
    switch (blockIdx.y) {
        case 0:  W = Wq;  bias = bq;  out = oq;  break;
        case 1:  W = Wk;  bias = bk;  out = okk; break;
        case 2:  W = Wv;  bias = bv;  out = ov;  break;
        default: W = Wsk; bias = bsk; out = osk; break;
    }
    const int tc = tid & 15, tr = tid >> 4;
    float acc[8][8];
    #pragma unroll
    for (int i = 0; i < 8; ++i)
        #pragma unroll
        for (int j = 0; j < 8; ++j) acc[i][j] = 0.f;

    for (int kc = 0; kc < 4; ++kc) {
        #pragma unroll
        for (int it = 0; it < 4; ++it) {
            int chunk = it*256 + tid;
            int row = chunk >> 3, c4 = chunk & 7;
            float4 g = make_float4(0.f,0.f,0.f,0.f);
            if (r0 + row < NN) g = ld4(&x[(r0+row)*CD + kc*32 + c4*4]);
            ast[(c4*4+0)*132 + row] = g.x;
            ast[(c4*4+1)*132 + row] = g.y;
            ast[(c4*4+2)*132 + row] = g.z;
            ast[(c4*4+3)*132 + row] = g.w;
        }
        #pragma unroll
        for (int it = 0; it < 4; ++it) {
            int chunk = it*256 + tid;
            int kr = chunk >> 5, c4 = chunk & 31;
            *(float4*)&bst[kr*132 + c4*4] = ld4(&W[(kc*32+kr)*CD + c4*4]);
        }
        __syncthreads();
        #pragma unroll
        for (int k = 0; k < 32; ++k) {
            float4 a0 = *(float4*)&ast[k*132 + tr*8];
            float4 a1 = *(float4*)&ast[k*132 + tr*8 + 4];
            float4 b0 = *(float4*)&bst[k*132 + tc*8];
            float4 b1 = *(float4*)&bst[k*132 + tc*8 + 4];
            float ar[8] = {a0.x,a0.y,a0.z,a0.w,a1.x,a1.y,a1.z,a1.w};
            float br[8] = {b0.x,b0.y,b0.z,b0.w,b1.x,b1.y,b1.z,b1.w};
            #pragma unroll
            for (int i = 0; i < 8; ++i)
                #pragma unroll
                for (int j = 0; j < 8; ++j)
                    acc[i][j] += ar[i]*br[j];
        }
        __syncthreads();
    }
    float bcol[8];
    #pragma unroll
    for (int j = 0; j < 8; ++j) bcol[j] = bias[tc*8+j];
    #pragma unroll
    for (int i = 0; i < 8; ++i) {
        int row = r0 + tr*8 + i;
        if (row < NN) {
            float4 o0 = make_float4(acc[i][0]+bcol[0], acc[i][1]+bcol[1],
                                    acc[i][2]+bcol[2], acc[i][3]+bcol[3]);
            float4 o1 = make_float4(acc[i][4]+bcol[4], acc[i][5]+bcol[5],
                                    acc[i][6]+bcol[6], acc[i][7]+bcol[7]);
            *(float4*)&out[row*CD + tc*8]     = o0;
            *(float4*)&out[row*CD + tc*8 + 4] = o1;
        }
    }
}

// ---------------- CSR build ----------------
__global__ __launch_bounds__(256) void hist_kernel(const int* __restrict__ ei, int* __restrict__ cnt)
{
    int j = blockIdx.x*blockDim.x + threadIdx.x;
    if (j < EE) atomicAdd(&cnt[ei[EE + j]], 1);
}

__global__ __launch_bounds__(256) void scan_kernel(int* __restrict__ cnt, int* __restrict__ off)
{
    __shared__ int part[256];
    const int t = threadIdx.x;
    const int nper = (NN + 255) / 256;
    const int lo = t*nper, hi = min(lo + nper, NN);
    int ssum = 0;
    for (int i = lo; i < hi; ++i) ssum += cnt[i];
    part[t] = ssum;
    __syncthreads();
    if (t == 0) {
        int run = 0;
        for (int i = 0; i < 256; ++i) { int tmp = part[i]; part[i] = run; run += tmp; }
    }
    __syncthreads();
    int run = part[t];
    for (int i = lo; i < hi; ++i) {
        int c = cnt[i];
        off[i] = run;
        cnt[i] = run;
        run += c;
    }
    if (hi == NN) off[NN] = run;
}

__global__ __launch_bounds__(256) void scatter_kernel(
    const int* __restrict__ ei, int* __restrict__ cur, int* __restrict__ elist)
{
    int j = blockIdx.x*blockDim.x + threadIdx.x;
    if (j < EE) {
        int pos = atomicAdd(&cur[ei[EE + j]], 1);
        elist[pos] = j;
    }
}

// ---------------- Alpha kernel (round-7 proven): e = ea@We tiled + scores ----------------
__global__ __launch_bounds__(256) void alpha_kernel(
    const float* __restrict__ ea, const int* __restrict__ ei,
    const float* __restrict__ We,
    const float* __restrict__ q, const float* __restrict__ kmat,
    float* __restrict__ aout)
{
    __shared__ float ast[32*132];
    __shared__ float bst[32*132];
    __shared__ int sidx[128];
    __shared__ int didx[128];
    const int tid = threadIdx.x;
    const int e0 = blockIdx.x * 128;
    const int ne = min(128, EE - e0);
    if (tid < 128) {
        sidx[tid] = (tid < ne) ? ei[e0 + tid] : 0;
    } else {
        int le = tid - 128;
        didx[le] = (le < ne) ? ei[EE + e0 + le] : 0;
    }
    const int tc = tid & 15, tr = tid >> 4;
    float acc[8][8];
    #pragma unroll
    for (int i = 0; i < 8; ++i)
        #pragma unroll
        for (int j = 0; j < 8; ++j) acc[i][j] = 0.f;

    for (int kc = 0; kc < 4; ++kc) {
        #pragma unroll
        for (int it = 0; it < 4; ++it) {
            int chunk = it*256 + tid;
            int le = chunk >> 3, c4 = chunk & 7;
            float4 g = make_float4(0.f,0.f,0.f,0.f);
            if (le < ne) g = ld4(&ea[(size_t)(e0+le)*CD + kc*32 + c4*4]);
            ast[(c4*4+0)*132 + le] = g.x;
            ast[(c4*4+1)*132 + le] = g.y;
            ast[(c4*4+2)*132 + le] = g.z;
            ast[(c4*4+3)*132 + le] = g.w;
        }
        #pragma unroll
        for (int it = 0; it < 4; ++it) {
            int chunk = it*256 + tid;
            int kr = chunk >> 5, c4 = chunk & 31;
            *(float4*)&bst[kr*132 + c4*4] = ld4(&We[(kc*32+kr)*CD + c4*4]);
        }
        __syncthreads();
        #pragma unroll
        for (int k = 0; k < 32; ++k) {
            float4 a0 = *(float4*)&ast[k*132 + tr*8];
            float4 a1 = *(float4*)&ast[k*132 + tr*8 + 4];
            float4 b0 = *(float4*)&bst[k*132 + tc*8];
            float4 b1 = *(float4*)&bst[k*132 + tc*8 + 4];
            float ar[8] = {a0.x,a0.y,a0.z,a0.w,a1.x,a1.y,a1.z,a1.w};
            float br[8] = {b0.x,b0.y,b0.z,b0.w,b1.x,b1.y,b1.z,b1.w};
            #pragma unroll
            for (int i = 0; i < 8; ++i)
                #pragma unroll
                for (int j = 0; j < 8; ++j)
                    acc[i][j] += ar[i]*br[j];
        }
        __syncthreads();
    }
    const int head = tc >> 2;
    const float inv_sqrt_o = 0.17677669529663687f;  // 1/sqrt(32)
    #pragma unroll
    for (int i = 0; i < 8; ++i) {
        int le = tr*8 + i;
        if (le < ne) {
            int sn = sidx[le], dn = didx[le];
            const float* qp = q    + dn*CD + tc*8;
            const float* kp = kmat + sn*CD + tc*8;
            float4 qa = ld4(qp), qb = ld4(qp+4);
            float4 ka = ld4(kp), kb = ld4(kp+4);
            float p =
                qa.x*(ka.x+acc[i][0]) + qa.y*(ka.y+acc[i][1]) +
                qa.z*(ka.z+acc[i][2]) + qa.w*(ka.w+acc[i][3]) +
                qb.x*(kb.x+acc[i][4]) + qb.y*(kb.y+acc[i][5]) +
                qb.z*(kb.z+acc[i][6]) + qb.w*(kb.w+acc[i][7]);
            p += __shfl_xor(p, 1);
            p += __shfl_xor(p, 2);
            float a = expf(p * inv_sqrt_o);
            if ((tc & 3) == 0) aout[(size_t)(e0+le)*4 + head] = a;
        }
    }
}

// ---------------- Node kernel: CSR walk with 16-edge shuffle-broadcast prefetch ----------------
__global__ __launch_bounds__(256) void node_kernel(
    const int* __restrict__ ei, const int* __restrict__ off, const int* __restrict__ elist,
    const float* __restrict__ a4, const float* __restrict__ ea,
    const float* __restrict__ vmat, const float* __restrict__ We,
    float* __restrict__ oa)
{
    __shared__ float s_lds[4][512];
    const int w = threadIdx.x >> 6;
    const int l = threadIdx.x & 63;
    const int n = blockIdx.x * 4 + w;
    if (n >= NN) return;
    const int beg = off[n], end = off[n+1];
    const int hsel = l >> 5;
    float s0k0=0,s1k0=0,s2k0=0,s3k0=0;
    float s0k1=0,s1k1=0,s2k1=0,s3k1=0;
    float av0=0, av1=0, den0=0, den1=0;
    for (int base = beg; base < end; base += 16) {
        const int nc = min(16, end - base);
        // parallel index prefetch: lanes 0-15 (replicated x4) fetch 16 elist entries,
        // then 16 src ids — removes the per-edge dependent scalar-load chain.
        const int sl = l & 15;
        int eidv = (sl < nc) ? elist[base + sl] : 0;
        int srcv = (sl < nc) ? ei[eidv] : 0;
        for (int t = 0; t < nc; ++t) {
            int eid = __shfl(eidv, t);   // broadcast from lane t (t < 16)
            int src = __shfl(srcv, t);
            float4 aq = ld4(&a4[(size_t)eid*4]);
            float ea0 = ea[(size_t)eid*CD + l];
            float ea1 = ea[(size_t)eid*CD + 64 + l];
            float v0  = vmat[(size_t)src*CD + l];
            float v1  = vmat[(size_t)src*CD + 64 + l];
            float aH0 = hsel ? aq.y : aq.x;
            float aH1 = hsel ? aq.w : aq.z;
            s0k0 += aq.x*ea0; s1k0 += aq.y*ea0; s2k0 += aq.z*ea0; s3k0 += aq.w*ea0;
            s0k1 += aq.x*ea1; s1k1 += aq.y*ea1; s2k1 += aq.z*ea1; s3k1 += aq.w*ea1;
            av0 += aH0*v0; av1 += aH1*v1;
            den0 += aH0;   den1 += aH1;
        }
    }
    s_lds[w][0*128 + l] = s0k0;  s_lds[w][0*128 + 64 + l] = s0k1;
    s_lds[w][1*128 + l] = s1k0;  s_lds[w][1*128 + 64 + l] = s1k1;
    s_lds[w][2*128 + l] = s2k0;  s_lds[w][2*128 + 64 + l] = s2k1;
    s_lds[w][3*128 + l] = s3k0;  s_lds[w][3*128 + 64 + l] = s3k1;
    const float* sh0 = &s_lds[w][hsel*128];
    const float* sh1 = &s_lds[w][(2+hsel)*128];
    float oe0 = 0.f, oe1 = 0.f;
    #pragma unroll 4
    for (int k = 0; k < 128; ++k) {
        oe0 += sh0[k] * We[k*CD + l];
        oe1 += sh1[k] * We[k*CD + 64 + l];
    }
    oa[(size_t)n*CD + l]      = (av0 + oe0) / (den0 + 1e-16f);
    oa[(size_t)n*CD + 64 + l] = (av1 + oe1) / (den1 + 1e-16f);
}

// ---------------- combine: beta-gate, residual, LN1 stats ----------------
__global__ __launch_bounds__(256) void combine_kernel(
    const float* __restrict__ x, const float* __restrict__ xr,
    const float* __restrict__ oa,
    const float* __restrict__ Wbeta, float* __restrict__ y, double* __restrict__ red)
{
    const int lane = threadIdx.x & 63;
    const int wid = blockIdx.x*4 + (threadIdx.x >> 6);
    const int nw = gridDim.x*4;
    const int c0 = lane, c1 = lane + 64;
    const float wb_o0 = Wbeta[c0],     wb_o1 = Wbeta[c1];
    const float wb_x0 = Wbeta[128+c0], wb_x1 = Wbeta[128+c1];
    const float wb_d0 = Wbeta[256+c0], wb_d1 = Wbeta[256+c1];
    float lsum = 0.f, lsq = 0.f;
    for (int n = wid; n < NN; n += nw) {
        float o0 = oa[n*CD+c0];
        float o1 = oa[n*CD+c1];
        float r0v = xr[n*CD+c0], r1v = xr[n*CD+c1];
        float d = o0*wb_o0 + r0v*wb_x0 + (o0-r0v)*wb_d0
                + o1*wb_o1 + r1v*wb_x1 + (o1-r1v)*wb_d1;
        #pragma unroll
        for (int off = 32; off; off >>= 1) d += __shfl_xor(d, off);
        float beta = 1.0f / (1.0f + expf(-d));
        float y0 = x[n*CD+c0] + beta*r0v + (1.0f-beta)*o0;
        float y1 = x[n*CD+c1] + beta*r1v + (1.0f-beta)*o1;
        y[n*CD+c0] = y0; y[n*CD+c1] = y1;
        lsum += y0 + y1; lsq += y0*y0 + y1*y1;
    }
    #pragma unroll
    for (int off = 32; off; off >>= 1) {
        lsum += __shfl_xor(lsum, off);
        lsq  += __shfl_xor(lsq,  off);
    }
    if (lane == 0) {
        atomicAdd(&red[0], (double)lsum);
        atomicAdd(&red[1], (double)lsq);
    }
}

// ---------------- FFN1: LN1(y) @ W1 + bf1, exact gelu -> h ----------------
__global__ __launch_bounds__(256) void ffn1_gemm(
    const float* __restrict__ y, const float* __restrict__ W1, const float* __restrict__ bf1,
    const float* __restrict__ lng, const float* __restrict__ lnb,
    const double* __restrict__ red, float* __restrict__ h)
{
    __shared__ float ast[32*132];
    __shared__ float bst[32*132];
    const int tid = threadIdx.x;
    const int r0 = blockIdx.x * 128;
    const int cb = blockIdx.y;
    double m = red[0] * (1.0/NCF);
    double var = red[1] * (1.0/NCF) - m*m;
    if (var < 0.0) var = 0.0;
    const float mean = (float)m;
    const float scale = (float)(1.0 / (sqrt(var) + 1e-5));
    const int tc = tid & 15, tr = tid >> 4;
    float acc[8][8];
    #pragma unroll
    for (int i = 0; i < 8; ++i)
        #pragma unroll
        for (int j = 0; j < 8; ++j) acc[i][j] = 0.f;

    for (int kc = 0; kc < 4; ++kc) {
        #pragma unroll
        for (int it = 0; it < 4; ++it) {
            int chunk = it*256 + tid;
            int row = chunk >> 3, c4 = chunk & 7;
            float4 g = make_float4(0.f,0.f,0.f,0.f);
            if (r0 + row < NN) g = ld4(&y[(r0+row)*CD + kc*32 + c4*4]);
            int col = kc*32 + c4*4;
            g.x = (g.x - mean)*scale*lng[col+0] + lnb[col+0];
            g.y = (g.y - mean)*scale*lng[col+1] + lnb[col+1];
            g.z = (g.z - mean)*scale*lng[col+2] + lnb[col+2];
            g.w = (g.w - mean)*scale*lng[col+3] + lnb[col+3];
            ast[(c4*4+0)*132 + row] = g.x;
            ast[(c4*4+1)*132 + row] = g.y;
            ast[(c4*4+2)*132 + row] = g.z;
            ast[(c4*4+3)*132 + row] = g.w;
        }
        #pragma unroll
        for (int it = 0; it < 4; ++it) {
            int chunk = it*256 + tid;
            int kr = chunk >> 5, c4 = chunk & 31;
            *(float4*)&bst[kr*132 + c4*4] = ld4(&W1[(size_t)(kc*32+kr)*FD + cb*128 + c4*4]);
        }
        __syncthreads();
        #pragma unroll
        for (int k = 0; k < 32; ++k) {
            float4 a0 = *(float4*)&ast[k*132 + tr*8];
            float4 a1 = *(float4*)&ast[k*132 + tr*8 + 4];
            float4 b0 = *(float4*)&bst[k*132 + tc*8];
            float4 b1 = *(float4*)&bst[k*132 + tc*8 + 4];
            float ar[8] = {a0.x,a0.y,a0.z,a0.w,a1.x,a1.y,a1.z,a1.w};
            float br[8] = {b0.x,b0.y,b0.z,b0.w,b1.x,b1.y,b1.z,b1.w};
            #pragma unroll
            for (int i = 0; i < 8; ++i)
                #pragma unroll
                for (int j = 0; j < 8; ++j)
                    acc[i][j] += ar[i]*br[j];
        }
        __syncthreads();
    }
    float bcol[8];
    #pragma unroll
    for (int j = 0; j < 8; ++j) bcol[j] = bf1[cb*128 + tc*8 + j];
    #pragma unroll
    for (int i = 0; i < 8; ++i) {
        int row = r0 + tr*8 + i;
        if (row < NN) {
            float o[8];
            #pragma unroll
            for (int j = 0; j < 8; ++j) {
                float hv = acc[i][j] + bcol[j];
                o[j] = 0.5f*hv*(1.0f + erff(hv*0.7071067811865476f));
            }
            float4 o0 = make_float4(o[0],o[1],o[2],o[3]);
            float4 o1 = make_float4(o[4],o[5],o[6],o[7]);
            *(float4*)&h[(size_t)row*FD + cb*128 + tc*8]     = o0;
            *(float4*)&h[(size_t)row*FD + cb*128 + tc*8 + 4] = o1;
        }
    }
}

// ---------------- FFN2: h @ W2 + bf2 + LN1(y), LN2 stats -> d_out ----------------
__global__ __launch_bounds__(256) void ffn2_gemm(
    const float* __restrict__ h, const float* __restrict__ W2, const float* __restrict__ bf2,
    const float* __restrict__ y, const float* __restrict__ lng, const float* __restrict__ lnb,
    double* __restrict__ red, float* __restrict__ outz)
{
    __shared__ float ast[32*132];
    __shared__ float bst[32*132];
    const int tid = threadIdx.x;
    const int r0 = blockIdx.x * 128;
    double m = red[0] * (1.0/NCF);
    double var = red[1] * (1.0/NCF) - m*m;
    if (var < 0.0) var = 0.0;
    const float mean = (float)m;
    const float scale = (float)(1.0 / (sqrt(var) + 1e-5));
    const int tc = tid & 15, tr = tid >> 4;
    float acc[8][8];
    #pragma unroll
    for (int i = 0; i < 8; ++i)
        #pragma unroll
        for (int j = 0; j < 8; ++j) acc[i][j] = 0.f;

    for (int kc = 0; kc < 16; ++kc) {
        #pragma unroll
        for (int it = 0; it < 4; ++it) {
            int chunk = it*256 + tid;
            int row = chunk >> 3, c4 = chunk & 7;
            float4 g = make_float4(0.f,0.f,0.f,0.f);
            if (r0 + row < NN) g = ld4(&h[(size_t)(r0+row)*FD + kc*32 + c4*4]);
            ast[(c4*4+0)*132 + row] = g.x;
            ast[(c4*4+1)*132 + row] = g.y;
            ast[(c4*4+2)*132 + row] = g.z;
            ast[(c4*4+3)*132 + row] = g.w;
        }
        #pragma unroll
        for (int it = 0; it < 4; ++it) {
            int chunk = it*256 + tid;
            int kr = chunk >> 5, c4 = chunk & 31;
            *(float4*)&bst[kr*132 + c4*4] = ld4(&W2[(size_t)(kc*32+kr)*CD + c4*4]);
        }
        __syncthreads();
        #pragma unroll
        for (int k = 0; k < 32; ++k) {
            float4 a0 = *(float4*)&ast[k*132 + tr*8];
            float4 a1 = *(float4*)&ast[k*132 + tr*8 + 4];
            float4 b0 = *(float4*)&bst[k*132 + tc*8];
            float4 b1 = *(float4*)&bst[k*132 + tc*8 + 4];
            float ar[8] = {a0.x,a0.y,a0.z,a0.w,a1.x,a1.y,a1.z,a1.w};
            float br[8] = {b0.x,b0.y,b0.z,b0.w,b1.x,b1.y,b1.z,b1.w};
            #pragma unroll
            for (int i = 0; i < 8; ++i)
                #pragma unroll
                for (int j = 0; j < 8; ++j)
                    acc[i][j] += ar[i]*br[j];
        }
        __syncthreads();
    }
    float g1c[8], b1c[8], bfc[8];
    #pragma unroll
    for (int j = 0; j < 8; ++j) {
        int col = tc*8 + j;
        g1c[j] = lng[col]; b1c[j] = lnb[col]; bfc[j] = bf2[col];
    }
    float lsum = 0.f, lsq = 0.f;
    #pragma unroll
    for (int i = 0; i < 8; ++i) {
        int row = r0 + tr*8 + i;
        if (row < NN) {
            float4 ya = ld4(&y[row*CD + tc*8]);
            float4 yb = ld4(&y[row*CD + tc*8 + 4]);
            float yv[8] = {ya.x,ya.y,ya.z,ya.w,yb.x,yb.y,yb.z,yb.w};
            float z[8];
            #pragma unroll
            for (int j = 0; j < 8; ++j) {
                float x1 = (yv[j] - mean)*scale*g1c[j] + b1c[j];
                z[j] = acc[i][j] + bfc[j] + x1;
                lsum += z[j]; lsq += z[j]*z[j];
            }
            float4 z0 = make_float4(z[0],z[1],z[2],z[3]);
            float4 z1 = make_float4(z[4],z[5],z[6],z[7]);
            *(float4*)&outz[row*CD + tc*8]     = z0;
            *(float4*)&outz[row*CD + tc*8 + 4] = z1;
        }
    }
    #pragma unroll
    for (int off = 32; off; off >>= 1) {
        lsum += __shfl_xor(lsum, off);
        lsq  += __shfl_xor(lsq,  off);
    }
    if ((threadIdx.x & 63) == 0) {
        atomicAdd(&red[2], (double)lsum);
        atomicAdd(&red[3], (double)lsq);
    }
}

// ---------------- LN2 in-place on d_out ----------------
__global__ __launch_bounds__(256) void ln2_kernel(
    float* __restrict__ z, const float* __restrict__ g2, const float* __restrict__ b2,
    const double* __restrict__ red)
{
    double m = red[2] * (1.0/NCF);
    double var = red[3] * (1.0/NCF) - m*m;
    if (var < 0.0) var = 0.0;
    const float mean = (float)m;
    const float scale = (float)(1.0 / (sqrt(var) + 1e-5));
    const int stride = gridDim.x * blockDim.x;
    for (int i = blockIdx.x*blockDim.x + threadIdx.x; i < NN*32; i += stride) {
        int c4 = (i & 31) * 4;
        float4 zv = *(float4*)&z[(size_t)i*4];
        float4 gv = ld4(&g2[c4]);
        float4 bv = ld4(&b2[c4]);
        zv.x = (zv.x - mean)*scale*gv.x + bv.x;
        zv.y = (zv.y - mean)*scale*gv.y + bv.y;
        zv.z = (zv.z - mean)*scale*gv.z + bv.z;
        zv.w = (zv.w - mean)*scale*gv.w + bv.w;
        *(float4*)&z[(size_t)i*4] = zv;
    }
}

extern "C" void kernel_launch(void* const* d_in, const int* in_sizes, int n_in,
                              void* d_out, int out_size, void* d_ws, size_t ws_size,
                              hipStream_t stream) {
    const float* x     = (const float*)d_in[0];
    const float* ea    = (const float*)d_in[1];
    const int*   ei    = (const int*)d_in[2];      // integers arrive as int32
    const float* Wq    = (const float*)d_in[3];
    const float* bq    = (const float*)d_in[4];
    const float* Wk    = (const float*)d_in[5];
    const float* bk    = (const float*)d_in[6];
    const float* Wv    = (const float*)d_in[7];
    const float* bv    = (const float*)d_in[8];
    const float* We    = (const float*)d_in[9];
    const float* Wsk   = (const float*)d_in[10];
    const float* bsk   = (const float*)d_in[11];
    const float* Wbeta = (const float*)d_in[12];
    const float* g1v   = (const float*)d_in[13];
    const float* be1   = (const float*)d_in[14];
    const float* g2v   = (const float*)d_in[15];
    const float* be2   = (const float*)d_in[16];
    const float* W1    = (const float*)d_in[17];
    const float* bf1   = (const float*)d_in[18];
    const float* W2    = (const float*)d_in[19];
    const float* bf2   = (const float*)d_in[20];

    float* wsf = (float*)d_ws;
    float* q    = wsf;                  // dead after alpha; reused as y
    float* kk   = wsf +  6400000;       // dead after alpha; h[0]
    float* vv   = wsf + 12800000;       // dead after node;  h[1]
    float* xr   = wsf + 19200000;       // dead after combine; h[2]
    float* oa   = wsf + 25600000;       // dead after combine; h[3]
    float* a4   = wsf + 32000000;       // per-edge exp scores (edge-major)
    int*   off  = (int*)(wsf + 34400000);  // 50001 ints
    int*   cur  = off + 50001;             // 50000 ints
    int*   elist= cur + 50000;             // 600000 ints
    double* red = (double*)(wsf + 35100056); // 8B-aligned
    float* y = q;
    float* h = kk;                      // h spans [6.4M, 32.0M) = N*512 floats
    float* zout = (float*)d_out;

    (void)hipMemsetAsync(cur, 0, 50000*sizeof(int), stream);
    (void)hipMemsetAsync(red, 0, 4*sizeof(double), stream);

    // CSR build
    hist_kernel<<<(EE+255)/256, 256, 0, stream>>>(ei, cur);
    scan_kernel<<<1, 256, 0, stream>>>(cur, off);
    scatter_kernel<<<(EE+255)/256, 256, 0, stream>>>(ei, cur, elist);

    dim3 gA((NN + 127)/128, 4);
    qkvs_gemm<<<gA, 256, 0, stream>>>(x, Wq,bq, Wk,bk, Wv,bv, Wsk,bsk, q, kk, vv, xr);

    alpha_kernel<<<(EE + 127)/128, 256, 0, stream>>>(ea, ei, We, q, kk, a4);

    node_kernel<<<(NN + 3)/4, 256, 0, stream>>>(ei, off, elist, a4, ea, vv, We, oa);

    combine_kernel<<<1024, 256, 0, stream>>>(x, xr, oa, Wbeta, y, red);

    dim3 gF((NN + 127)/128, 4);
    ffn1_gemm<<<gF, 256, 0, stream>>>(y, W1, bf1, g1v, be1, red, h);

    ffn2_gemm<<<(NN + 127)/128, 256, 0, stream>>>(h, W2, bf2, y, g1v, be1, red, zout);

    ln2_kernel<<<2048, 256, 0, stream>>>(zout, g2v, be2, red);
}